// Round 1
// baseline (2822.817 us; speedup 1.0000x reference)
//
#include <hip/hip_runtime.h>

// GCN layer aggregation:
//   node_f = concat(u_f, v_f)                      [N,128] f32
//   out    = diag(in_deg^-1/2) * A * diag(out_deg^-1/2) * node_f
// Strategy: atomics baseline.
//   K1: degree histograms (int atomics)
//   K2: edge-parallel scatter-add (32 lanes/edge, float4 gather, 4 f32 atomics/lane)
//   K3: in-degree rescale (float4 RMW)

#define DFEAT 128

__global__ void degree_kernel(const int* __restrict__ src,
                              const int* __restrict__ dst,
                              int* __restrict__ odeg,
                              int* __restrict__ ideg,
                              int nE) {
    int e = blockIdx.x * blockDim.x + threadIdx.x;
    if (e < nE) {
        atomicAdd(&odeg[src[e]], 1);
        atomicAdd(&ideg[dst[e]], 1);
    }
}

// 256 threads/block = 8 edges/block, 32 lanes per edge (one float4 each).
__global__ void scatter_kernel(const float* __restrict__ u_f,
                               const float* __restrict__ v_f,
                               const int* __restrict__ src,
                               const int* __restrict__ dst,
                               const int* __restrict__ odeg,
                               float* __restrict__ out,
                               int nE, int nU) {
    int lane = threadIdx.x & 31;
    int sub  = threadIdx.x >> 5;
    long e = (long)blockIdx.x * 8 + sub;
    if (e >= nE) return;

    int s = src[e];
    int d = dst[e];
    float norm = rsqrtf((float)max(odeg[s], 1));

    const float* row = (s < nU) ? (u_f + (size_t)s * DFEAT)
                                : (v_f + (size_t)(s - nU) * DFEAT);
    float4 val = ((const float4*)row)[lane];

    float* orow = out + (size_t)d * DFEAT + (size_t)lane * 4;
    atomicAdd(orow + 0, val.x * norm);
    atomicAdd(orow + 1, val.y * norm);
    atomicAdd(orow + 2, val.z * norm);
    atomicAdd(orow + 3, val.w * norm);
}

// One float4 per thread over N*32 float4s.
__global__ void scale_kernel(float* __restrict__ out,
                             const int* __restrict__ ideg,
                             long n4) {
    long i = (long)blockIdx.x * blockDim.x + threadIdx.x;
    if (i >= n4) return;
    int node = (int)(i >> 5);  // 32 float4s per node row
    float norm = rsqrtf((float)max(ideg[node], 1));
    float4 v = ((float4*)out)[i];
    v.x *= norm; v.y *= norm; v.z *= norm; v.w *= norm;
    ((float4*)out)[i] = v;
}

extern "C" void kernel_launch(void* const* d_in, const int* in_sizes, int n_in,
                              void* d_out, int out_size, void* d_ws, size_t ws_size,
                              hipStream_t stream) {
    const float* u_f = (const float*)d_in[0];
    const float* v_f = (const float*)d_in[1];
    const int*   src = (const int*)d_in[2];
    const int*   dst = (const int*)d_in[3];
    float* out = (float*)d_out;

    int nU = in_sizes[0] / DFEAT;
    int nV = in_sizes[1] / DFEAT;
    int nN = nU + nV;
    int nE = in_sizes[2];

    int* odeg = (int*)d_ws;
    int* ideg = odeg + nN;

    // Zero degree scratch and output accumulator (ws/out are poisoned 0xAA).
    hipMemsetAsync(d_ws, 0, (size_t)2 * nN * sizeof(int), stream);
    hipMemsetAsync(d_out, 0, (size_t)out_size * sizeof(float), stream);

    // K1: degrees
    {
        int threads = 256;
        int blocks = (nE + threads - 1) / threads;
        degree_kernel<<<blocks, threads, 0, stream>>>(src, dst, odeg, ideg, nE);
    }

    // K2: scatter-add
    {
        int threads = 256;                 // 8 edges per block
        int blocks = (nE + 7) / 8;
        scatter_kernel<<<blocks, threads, 0, stream>>>(u_f, v_f, src, dst, odeg,
                                                       out, nE, nU);
    }

    // K3: in-degree rescale
    {
        long n4 = (long)nN * (DFEAT / 4);
        int threads = 256;
        int blocks = (int)((n4 + threads - 1) / threads);
        scale_kernel<<<blocks, threads, 0, stream>>>(out, ideg, n4);
    }
}

// Round 2
// 476.759 us; speedup vs baseline: 5.9208x; 5.9208x over previous
//
#include <hip/hip_runtime.h>

// GCN aggregation, CSR gather-sum version (no f32 atomics).
//   out = diag(in_deg^-1/2) * A * diag(out_deg^-1/2) * concat(u_f, v_f)
//
// K1 degree histograms -> K2 exclusive scan (offs, cursor) -> K3 CSR build
// -> K4 wave-per-node gather/sum with fused normalizations.
//
// Workspace layout (ints): odeg[nN] | ideg[nN] | offs[nN+1] | cursor[nN] | csr_src[nE]
//   = 4*nN + 1 + nE ints  (~8 MB for nN=100K, nE=1.6M)

#define DFEAT 128

__global__ void degree_kernel(const int* __restrict__ src,
                              const int* __restrict__ dst,
                              int* __restrict__ odeg,
                              int* __restrict__ ideg,
                              int nE) {
    int e = blockIdx.x * blockDim.x + threadIdx.x;
    if (e < nE) {
        atomicAdd(&odeg[src[e]], 1);
        atomicAdd(&ideg[dst[e]], 1);
    }
}

// Single-block exclusive scan of deg[0..n) -> offs[0..n], also writes cursor=offs.
// 1024 threads, shfl wave-scan + LDS scan of 16 wave sums.
__global__ void scan_kernel(const int* __restrict__ deg,
                            int* __restrict__ offs,
                            int* __restrict__ cursor,
                            int n) {
    __shared__ int wsum[16];
    __shared__ int chunk_total;
    __shared__ int carry_s;
    int tid = threadIdx.x;
    int lane = tid & 63, wid = tid >> 6;
    if (tid == 0) carry_s = 0;
    __syncthreads();

    for (int base = 0; base < n; base += 1024) {
        int i = base + tid;
        int v = (i < n) ? deg[i] : 0;
        // inclusive scan within wave
        int x = v;
        #pragma unroll
        for (int off = 1; off < 64; off <<= 1) {
            int t = __shfl_up(x, off, 64);
            if (lane >= off) x += t;
        }
        if (lane == 63) wsum[wid] = x;
        __syncthreads();
        if (tid == 0) {
            int acc = 0;
            #pragma unroll
            for (int w = 0; w < 16; ++w) { int t = wsum[w]; wsum[w] = acc; acc += t; }
            chunk_total = acc;
        }
        __syncthreads();
        int excl = carry_s + wsum[wid] + (x - v);
        if (i < n) { offs[i] = excl; cursor[i] = excl; }
        __syncthreads();                 // everyone has read carry_s
        if (tid == 0) carry_s += chunk_total;
        __syncthreads();
    }
    if (tid == 0) offs[n] = carry_s;
}

__global__ void csr_build_kernel(const int* __restrict__ src,
                                 const int* __restrict__ dst,
                                 int* __restrict__ cursor,
                                 int* __restrict__ csr_src,
                                 int nE) {
    int e = blockIdx.x * blockDim.x + threadIdx.x;
    if (e < nE) {
        int p = atomicAdd(&cursor[dst[e]], 1);
        csr_src[p] = src[e];
    }
}

// One 64-lane wave per destination node; 4 waves (256 thr) per block.
// Each lane accumulates float2 (64*2 = 128 features).
__launch_bounds__(256)
__global__ void aggregate_kernel(const float* __restrict__ u_f,
                                 const float* __restrict__ v_f,
                                 const int* __restrict__ csr_src,
                                 const int* __restrict__ offs,
                                 const int* __restrict__ odeg,
                                 float* __restrict__ out,
                                 int nN, int nU) {
    int lane = threadIdx.x & 63;
    int wid  = threadIdx.x >> 6;
    int node = blockIdx.x * 4 + wid;
    if (node >= nN) return;

    int beg = offs[node];
    int end = offs[node + 1];

    float2 acc = make_float2(0.f, 0.f);

    int p = beg;
    while (p < end) {
        int cnt = end - p;
        if (cnt > 64) cnt = 64;
        // lane-parallel batch load of src ids + their out-norms
        int   sb = 0;
        float nb = 0.f;
        if (lane < cnt) {
            sb = csr_src[p + lane];
            nb = rsqrtf((float)max(odeg[sb], 1));
        }
        for (int k = 0; k < cnt; ++k) {
            int   sk = __shfl(sb, k, 64);
            float nk = __shfl(nb, k, 64);
            const float* row = (sk < nU) ? (u_f + (size_t)sk * DFEAT)
                                         : (v_f + (size_t)(sk - nU) * DFEAT);
            float2 v = ((const float2*)row)[lane];
            acc.x += v.x * nk;
            acc.y += v.y * nk;
        }
        p += cnt;
    }

    int indeg = end - beg;
    float inorm = rsqrtf((float)max(indeg, 1));
    acc.x *= inorm; acc.y *= inorm;
    ((float2*)(out + (size_t)node * DFEAT))[lane] = acc;
}

extern "C" void kernel_launch(void* const* d_in, const int* in_sizes, int n_in,
                              void* d_out, int out_size, void* d_ws, size_t ws_size,
                              hipStream_t stream) {
    const float* u_f = (const float*)d_in[0];
    const float* v_f = (const float*)d_in[1];
    const int*   src = (const int*)d_in[2];
    const int*   dst = (const int*)d_in[3];
    float* out = (float*)d_out;

    int nU = in_sizes[0] / DFEAT;
    int nV = in_sizes[1] / DFEAT;
    int nN = nU + nV;
    int nE = in_sizes[2];

    int* odeg    = (int*)d_ws;
    int* ideg    = odeg + nN;
    int* offs    = ideg + nN;          // nN+1
    int* cursor  = offs + nN + 1;
    int* csr_src = cursor + nN;

    // zero the degree histograms (ws is poisoned 0xAA, never re-poisoned)
    hipMemsetAsync(d_ws, 0, (size_t)2 * nN * sizeof(int), stream);

    {   // K1: degrees
        int threads = 256;
        int blocks = (nE + threads - 1) / threads;
        degree_kernel<<<blocks, threads, 0, stream>>>(src, dst, odeg, ideg, nE);
    }
    {   // K2: scan ideg -> offs, cursor
        scan_kernel<<<1, 1024, 0, stream>>>(ideg, offs, cursor, nN);
    }
    {   // K3: CSR build
        int threads = 256;
        int blocks = (nE + threads - 1) / threads;
        csr_build_kernel<<<blocks, threads, 0, stream>>>(src, dst, cursor, csr_src, nE);
    }
    {   // K4: aggregate (writes every output element; no memset of d_out needed)
        int threads = 256;                  // 4 waves = 4 nodes per block
        int blocks = (nN + 3) / 4;
        aggregate_kernel<<<blocks, threads, 0, stream>>>(u_f, v_f, csr_src, offs,
                                                         odeg, out, nN, nU);
    }
}

// Round 3
// 381.438 us; speedup vs baseline: 7.4005x; 1.2499x over previous
//
#include <hip/hip_runtime.h>

// GCN aggregation, CSR gather-sum, parallel scan version.
//   out = diag(in_deg^-1/2) * A * diag(out_deg^-1/2) * concat(u_f, v_f)
//
// K1 degree histograms -> K2a/b/c 3-pass exclusive scan -> Knorm out-norms
// -> K3 CSR build -> K4 wave-per-node gather/sum with fused normalizations.
//
// Workspace (ints): odeg[nN] | ideg[nN] | offs[nN+1] | cursor[nN] | onorm[nN](f32)
//                   | bsum[NB] | boff[NB] | csr_src[nE]

#define DFEAT 128
#define SCAN_ELEMS 1024   // elements per scan block (256 thr x 4)

__global__ void degree_kernel(const int* __restrict__ src,
                              const int* __restrict__ dst,
                              int* __restrict__ odeg,
                              int* __restrict__ ideg,
                              int nE) {
    int e = blockIdx.x * blockDim.x + threadIdx.x;
    if (e < nE) {
        atomicAdd(&odeg[src[e]], 1);
        atomicAdd(&ideg[dst[e]], 1);
    }
}

// K2a: per-block sums of deg (SCAN_ELEMS per block)
__global__ void block_reduce_kernel(const int* __restrict__ deg,
                                    int* __restrict__ bsum, int n) {
    int tid = threadIdx.x;
    int base = blockIdx.x * SCAN_ELEMS + tid * 4;
    int s = 0;
    #pragma unroll
    for (int j = 0; j < 4; ++j) {
        int i = base + j;
        if (i < n) s += deg[i];
    }
    #pragma unroll
    for (int off = 32; off; off >>= 1) s += __shfl_down(s, off, 64);
    __shared__ int ws[4];
    int lane = tid & 63, wid = tid >> 6;
    if (lane == 0) ws[wid] = s;
    __syncthreads();
    if (tid == 0) bsum[blockIdx.x] = ws[0] + ws[1] + ws[2] + ws[3];
}

// K2b: single-block exclusive scan of bsum[nb] -> boff; total -> *total_out.
// nb <= 1024.
__global__ void scan_bsums_kernel(const int* __restrict__ bsum,
                                  int* __restrict__ boff,
                                  int* __restrict__ total_out, int nb) {
    int tid = threadIdx.x;
    int v = (tid < nb) ? bsum[tid] : 0;
    int lane = tid & 63, wid = tid >> 6;
    int x = v;
    #pragma unroll
    for (int off = 1; off < 64; off <<= 1) {
        int t = __shfl_up(x, off, 64);
        if (lane >= off) x += t;
    }
    __shared__ int ws[16];
    __shared__ int wpre[16];
    if (lane == 63) ws[wid] = x;
    __syncthreads();
    if (tid == 0) {
        int acc = 0;
        #pragma unroll
        for (int w = 0; w < 16; ++w) { int t = ws[w]; wpre[w] = acc; acc += t; }
    }
    __syncthreads();
    int excl = wpre[wid] + (x - v);
    if (tid < nb) boff[tid] = excl;
    if (tid == nb - 1) *total_out = excl + v;
}

// K2c: per-block local scan + block offset -> offs, cursor
__global__ void block_scan_kernel(const int* __restrict__ deg,
                                  const int* __restrict__ boff,
                                  int* __restrict__ offs,
                                  int* __restrict__ cursor, int n) {
    int tid = threadIdx.x;
    int base = blockIdx.x * SCAN_ELEMS + tid * 4;
    int v[4];
    int s = 0;
    #pragma unroll
    for (int j = 0; j < 4; ++j) {
        int i = base + j;
        v[j] = (i < n) ? deg[i] : 0;
        s += v[j];
    }
    int lane = tid & 63, wid = tid >> 6;
    int x = s;
    #pragma unroll
    for (int off = 1; off < 64; off <<= 1) {
        int t = __shfl_up(x, off, 64);
        if (lane >= off) x += t;
    }
    __shared__ int ws[4];
    if (lane == 63) ws[wid] = x;
    __syncthreads();
    int wp = 0;
    for (int w = 0; w < wid; ++w) wp += ws[w];
    int excl = boff[blockIdx.x] + wp + (x - s);
    #pragma unroll
    for (int j = 0; j < 4; ++j) {
        int i = base + j;
        if (i < n) { offs[i] = excl; cursor[i] = excl; }
        excl += v[j];
    }
}

__global__ void onorm_kernel(const int* __restrict__ odeg,
                             float* __restrict__ onorm, int n) {
    int i = blockIdx.x * blockDim.x + threadIdx.x;
    if (i < n) onorm[i] = rsqrtf((float)max(odeg[i], 1));
}

__global__ void csr_build_kernel(const int* __restrict__ src,
                                 const int* __restrict__ dst,
                                 int* __restrict__ cursor,
                                 int* __restrict__ csr_src,
                                 int nE) {
    int e = blockIdx.x * blockDim.x + threadIdx.x;
    if (e < nE) {
        int p = atomicAdd(&cursor[dst[e]], 1);
        csr_src[p] = src[e];
    }
}

// One 64-lane wave per destination node; 4 waves (256 thr) per block.
__launch_bounds__(256)
__global__ void aggregate_kernel(const float* __restrict__ u_f,
                                 const float* __restrict__ v_f,
                                 const int* __restrict__ csr_src,
                                 const int* __restrict__ offs,
                                 const float* __restrict__ onorm,
                                 float* __restrict__ out,
                                 int nN, int nU) {
    int lane = threadIdx.x & 63;
    int wid  = threadIdx.x >> 6;
    int node = blockIdx.x * 4 + wid;
    if (node >= nN) return;

    int beg = offs[node];
    int end = offs[node + 1];

    float2 acc = make_float2(0.f, 0.f);

    int p = beg;
    while (p < end) {
        int cnt = end - p;
        if (cnt > 64) cnt = 64;
        int   sb = 0;
        float nb = 0.f;
        if (lane < cnt) {
            sb = csr_src[p + lane];
            nb = onorm[sb];
        }
        for (int k = 0; k < cnt; ++k) {
            int   sk = __shfl(sb, k, 64);
            float nk = __shfl(nb, k, 64);
            const float* row = (sk < nU) ? (u_f + (size_t)sk * DFEAT)
                                         : (v_f + (size_t)(sk - nU) * DFEAT);
            float2 v = ((const float2*)row)[lane];
            acc.x += v.x * nk;
            acc.y += v.y * nk;
        }
        p += cnt;
    }

    float inorm = rsqrtf((float)max(end - beg, 1));
    acc.x *= inorm; acc.y *= inorm;
    ((float2*)(out + (size_t)node * DFEAT))[lane] = acc;
}

extern "C" void kernel_launch(void* const* d_in, const int* in_sizes, int n_in,
                              void* d_out, int out_size, void* d_ws, size_t ws_size,
                              hipStream_t stream) {
    const float* u_f = (const float*)d_in[0];
    const float* v_f = (const float*)d_in[1];
    const int*   src = (const int*)d_in[2];
    const int*   dst = (const int*)d_in[3];
    float* out = (float*)d_out;

    int nU = in_sizes[0] / DFEAT;
    int nV = in_sizes[1] / DFEAT;
    int nN = nU + nV;
    int nE = in_sizes[2];
    int NB = (nN + SCAN_ELEMS - 1) / SCAN_ELEMS;   // scan blocks (<=1024)

    int*   odeg    = (int*)d_ws;
    int*   ideg    = odeg + nN;
    int*   offs    = ideg + nN;            // nN+1
    int*   cursor  = offs + nN + 1;
    float* onorm   = (float*)(cursor + nN);
    int*   bsum    = (int*)(onorm + nN);
    int*   boff    = bsum + NB;
    int*   csr_src = boff + NB;

    // zero degree histograms (ws is poisoned 0xAA, never re-poisoned)
    hipMemsetAsync(d_ws, 0, (size_t)2 * nN * sizeof(int), stream);

    {   // K1: degrees
        int blocks = (nE + 255) / 256;
        degree_kernel<<<blocks, 256, 0, stream>>>(src, dst, odeg, ideg, nE);
    }
    {   // K2: 3-pass exclusive scan of ideg -> offs/cursor
        block_reduce_kernel<<<NB, 256, 0, stream>>>(ideg, bsum, nN);
        scan_bsums_kernel<<<1, 1024, 0, stream>>>(bsum, boff, offs + nN, NB);
        block_scan_kernel<<<NB, 256, 0, stream>>>(ideg, boff, offs, cursor, nN);
    }
    {   // Knorm: out-degree norms
        int blocks = (nN + 255) / 256;
        onorm_kernel<<<blocks, 256, 0, stream>>>(odeg, onorm, nN);
    }
    {   // K3: CSR build
        int blocks = (nE + 255) / 256;
        csr_build_kernel<<<blocks, 256, 0, stream>>>(src, dst, cursor, csr_src, nE);
    }
    {   // K4: aggregate (writes every output element)
        int blocks = (nN + 3) / 4;
        aggregate_kernel<<<blocks, 256, 0, stream>>>(u_f, v_f, csr_src, offs,
                                                     onorm, out, nN, nU);
    }
}

// Round 4
// 343.026 us; speedup vs baseline: 8.2292x; 1.1120x over previous
//
#include <hip/hip_runtime.h>

// GCN aggregation, CSR gather-sum, bf16-prescaled node table.
//   out = diag(in_deg^-1/2) * A * diag(out_deg^-1/2) * concat(u_f, v_f)
//
// K1 degree histograms -> K2a/b/c scan(ideg) -> Kcast bf16(node_f * onorm)
// -> K3 CSR build -> K4 wave-per-node bf16 gather/sum (fused in-norm).
//
// Workspace (ints): ideg[nN] | odeg[nN] | offs[nN+1] | cursor[nN]
//                   | bsum[NB] | boff[NB] | csr_src[nE] | node_bf (ushort[nN*128])

#define DFEAT 128
#define SCAN_ELEMS 1024   // elements per scan block (256 thr x 4)

__global__ void degree_kernel(const int* __restrict__ src,
                              const int* __restrict__ dst,
                              int* __restrict__ ideg,
                              int* __restrict__ odeg,
                              int nE) {
    int e = blockIdx.x * blockDim.x + threadIdx.x;
    if (e < nE) {
        atomicAdd(&odeg[src[e]], 1);
        atomicAdd(&ideg[dst[e]], 1);
    }
}

// K2a: per-block sums of deg
__global__ void block_reduce_kernel(const int* __restrict__ deg,
                                    int* __restrict__ bsum, int n) {
    int tid = threadIdx.x;
    int base = blockIdx.x * SCAN_ELEMS + tid * 4;
    int s = 0;
    #pragma unroll
    for (int j = 0; j < 4; ++j) {
        int i = base + j;
        if (i < n) s += deg[i];
    }
    #pragma unroll
    for (int off = 32; off; off >>= 1) s += __shfl_down(s, off, 64);
    __shared__ int ws[4];
    int lane = tid & 63, wid = tid >> 6;
    if (lane == 0) ws[wid] = s;
    __syncthreads();
    if (tid == 0) bsum[blockIdx.x] = ws[0] + ws[1] + ws[2] + ws[3];
}

// K2b: single-block exclusive scan of bsum[nb] (nb <= 1024)
__global__ void scan_bsums_kernel(const int* __restrict__ bsum,
                                  int* __restrict__ boff,
                                  int* __restrict__ total_out, int nb) {
    int tid = threadIdx.x;
    int v = (tid < nb) ? bsum[tid] : 0;
    int lane = tid & 63, wid = tid >> 6;
    int x = v;
    #pragma unroll
    for (int off = 1; off < 64; off <<= 1) {
        int t = __shfl_up(x, off, 64);
        if (lane >= off) x += t;
    }
    __shared__ int ws[16];
    __shared__ int wpre[16];
    if (lane == 63) ws[wid] = x;
    __syncthreads();
    if (tid == 0) {
        int acc = 0;
        #pragma unroll
        for (int w = 0; w < 16; ++w) { int t = ws[w]; wpre[w] = acc; acc += t; }
    }
    __syncthreads();
    int excl = wpre[wid] + (x - v);
    if (tid < nb) boff[tid] = excl;
    if (tid == nb - 1) *total_out = excl + v;
}

// K2c: per-block local scan + block offset -> offs, cursor
__global__ void block_scan_kernel(const int* __restrict__ deg,
                                  const int* __restrict__ boff,
                                  int* __restrict__ offs,
                                  int* __restrict__ cursor, int n) {
    int tid = threadIdx.x;
    int base = blockIdx.x * SCAN_ELEMS + tid * 4;
    int v[4];
    int s = 0;
    #pragma unroll
    for (int j = 0; j < 4; ++j) {
        int i = base + j;
        v[j] = (i < n) ? deg[i] : 0;
        s += v[j];
    }
    int lane = tid & 63, wid = tid >> 6;
    int x = s;
    #pragma unroll
    for (int off = 1; off < 64; off <<= 1) {
        int t = __shfl_up(x, off, 64);
        if (lane >= off) x += t;
    }
    __shared__ int ws[4];
    if (lane == 63) ws[wid] = x;
    __syncthreads();
    int wp = 0;
    for (int w = 0; w < wid; ++w) wp += ws[w];
    int excl = boff[blockIdx.x] + wp + (x - s);
    #pragma unroll
    for (int j = 0; j < 4; ++j) {
        int i = base + j;
        if (i < n) { offs[i] = excl; cursor[i] = excl; }
        excl += v[j];
    }
}

__device__ __forceinline__ unsigned short f2bf(float x) {
    unsigned u = __float_as_uint(x);
    u += 0x7fffu + ((u >> 16) & 1u);   // round-to-nearest-even
    return (unsigned short)(u >> 16);
}

// Kcast: node_bf[n][128] = bf16(node_f[n] * rsqrt(max(odeg,1)))
// one thread per float4 (32 threads per node row)
__global__ void cast_kernel(const float* __restrict__ u_f,
                            const float* __restrict__ v_f,
                            const int* __restrict__ odeg,
                            unsigned short* __restrict__ node_bf,
                            int nN, int nU) {
    long i = (long)blockIdx.x * blockDim.x + threadIdx.x;   // float4 index
    long n4 = (long)nN * (DFEAT / 4);
    if (i >= n4) return;
    int node = (int)(i >> 5);                               // 32 float4 per row
    float norm = rsqrtf((float)max(odeg[node], 1));
    const float* base = (node < nU) ? (u_f + (size_t)node * DFEAT)
                                    : (v_f + (size_t)(node - nU) * DFEAT);
    float4 v = ((const float4*)base)[i & 31];
    ushort4 o;
    o.x = f2bf(v.x * norm);
    o.y = f2bf(v.y * norm);
    o.z = f2bf(v.z * norm);
    o.w = f2bf(v.w * norm);
    ((ushort4*)node_bf)[i] = o;
}

__global__ void csr_build_kernel(const int* __restrict__ src,
                                 const int* __restrict__ dst,
                                 int* __restrict__ cursor,
                                 int* __restrict__ csr_src,
                                 int nE) {
    int e = blockIdx.x * blockDim.x + threadIdx.x;
    if (e < nE) {
        int p = atomicAdd(&cursor[dst[e]], 1);
        csr_src[p] = src[e];
    }
}

// K4: one wave per dst node, bf16 table, 4 waves per block.
// Each lane reads one uint (2 bf16) per source row; acc in f32.
__launch_bounds__(256)
__global__ void aggregate_bf_kernel(const unsigned short* __restrict__ node_bf,
                                    const int* __restrict__ csr_src,
                                    const int* __restrict__ offs,
                                    float* __restrict__ out,
                                    int nN) {
    int lane = threadIdx.x & 63;
    int wid  = threadIdx.x >> 6;
    int node = blockIdx.x * 4 + wid;
    if (node >= nN) return;

    int beg = offs[node];
    int end = offs[node + 1];

    float accx = 0.f, accy = 0.f;
    const unsigned* tbl = (const unsigned*)node_bf;   // 64 uints per row

    int p = beg;
    while (p < end) {
        int cnt = end - p;
        if (cnt > 64) cnt = 64;
        int sb = (lane < cnt) ? csr_src[p + lane] : 0;

        int k = 0;
        for (; k + 2 <= cnt; k += 2) {
            int sk0 = __shfl(sb, k, 64);
            int sk1 = __shfl(sb, k + 1, 64);
            unsigned w0 = tbl[(size_t)sk0 * 64 + lane];
            unsigned w1 = tbl[(size_t)sk1 * 64 + lane];
            accx += __uint_as_float(w0 << 16);
            accy += __uint_as_float(w0 & 0xffff0000u);
            accx += __uint_as_float(w1 << 16);
            accy += __uint_as_float(w1 & 0xffff0000u);
        }
        if (k < cnt) {
            int sk = __shfl(sb, k, 64);
            unsigned w = tbl[(size_t)sk * 64 + lane];
            accx += __uint_as_float(w << 16);
            accy += __uint_as_float(w & 0xffff0000u);
        }
        p += cnt;
    }

    float inorm = rsqrtf((float)max(end - beg, 1));
    float2 o = make_float2(accx * inorm, accy * inorm);
    ((float2*)(out + (size_t)node * DFEAT))[lane] = o;
}

// Fallback (small ws): f32 gather with inline out-norm.
__launch_bounds__(256)
__global__ void aggregate_f32_kernel(const float* __restrict__ u_f,
                                     const float* __restrict__ v_f,
                                     const int* __restrict__ csr_src,
                                     const int* __restrict__ offs,
                                     const int* __restrict__ odeg,
                                     float* __restrict__ out,
                                     int nN, int nU) {
    int lane = threadIdx.x & 63;
    int wid  = threadIdx.x >> 6;
    int node = blockIdx.x * 4 + wid;
    if (node >= nN) return;

    int beg = offs[node];
    int end = offs[node + 1];
    float2 acc = make_float2(0.f, 0.f);

    int p = beg;
    while (p < end) {
        int cnt = end - p;
        if (cnt > 64) cnt = 64;
        int   sb = 0;
        float nb = 0.f;
        if (lane < cnt) {
            sb = csr_src[p + lane];
            nb = rsqrtf((float)max(odeg[sb], 1));
        }
        for (int k = 0; k < cnt; ++k) {
            int   sk = __shfl(sb, k, 64);
            float nk = __shfl(nb, k, 64);
            const float* row = (sk < nU) ? (u_f + (size_t)sk * DFEAT)
                                         : (v_f + (size_t)(sk - nU) * DFEAT);
            float2 v = ((const float2*)row)[lane];
            acc.x += v.x * nk;
            acc.y += v.y * nk;
        }
        p += cnt;
    }

    float inorm = rsqrtf((float)max(end - beg, 1));
    acc.x *= inorm; acc.y *= inorm;
    ((float2*)(out + (size_t)node * DFEAT))[lane] = acc;
}

extern "C" void kernel_launch(void* const* d_in, const int* in_sizes, int n_in,
                              void* d_out, int out_size, void* d_ws, size_t ws_size,
                              hipStream_t stream) {
    const float* u_f = (const float*)d_in[0];
    const float* v_f = (const float*)d_in[1];
    const int*   src = (const int*)d_in[2];
    const int*   dst = (const int*)d_in[3];
    float* out = (float*)d_out;

    int nU = in_sizes[0] / DFEAT;
    int nV = in_sizes[1] / DFEAT;
    int nN = nU + nV;
    int nE = in_sizes[2];
    int NB = (nN + SCAN_ELEMS - 1) / SCAN_ELEMS;

    int* ideg    = (int*)d_ws;
    int* odeg    = ideg + nN;
    int* offs    = odeg + nN;          // nN+1
    int* cursor  = offs + nN + 1;
    int* bsum    = cursor + nN;
    int* boff    = bsum + NB;
    int* csr_src = boff + NB;
    // bf16 table after csr_src, 16B aligned
    size_t bf_off = (((size_t)(csr_src + nE) - (size_t)d_ws) + 15) & ~(size_t)15;
    unsigned short* node_bf = (unsigned short*)((char*)d_ws + bf_off);
    size_t need = bf_off + (size_t)nN * DFEAT * sizeof(unsigned short);
    bool use_bf = (ws_size >= need);

    // zero degree histograms (ideg|odeg adjacent)
    hipMemsetAsync(d_ws, 0, (size_t)2 * nN * sizeof(int), stream);

    {   // K1: degrees
        int blocks = (nE + 255) / 256;
        degree_kernel<<<blocks, 256, 0, stream>>>(src, dst, ideg, odeg, nE);
    }
    {   // K2: scan ideg -> offs/cursor
        block_reduce_kernel<<<NB, 256, 0, stream>>>(ideg, bsum, nN);
        scan_bsums_kernel<<<1, 1024, 0, stream>>>(bsum, boff, offs + nN, NB);
        block_scan_kernel<<<NB, 256, 0, stream>>>(ideg, boff, offs, cursor, nN);
    }
    if (use_bf) {   // Kcast: bf16 prescaled node table
        long n4 = (long)nN * (DFEAT / 4);
        int blocks = (int)((n4 + 255) / 256);
        cast_kernel<<<blocks, 256, 0, stream>>>(u_f, v_f, odeg, node_bf, nN, nU);
    }
    {   // K3: CSR build
        int blocks = (nE + 255) / 256;
        csr_build_kernel<<<blocks, 256, 0, stream>>>(src, dst, cursor, csr_src, nE);
    }
    {   // K4: aggregate
        int blocks = (nN + 3) / 4;
        if (use_bf)
            aggregate_bf_kernel<<<blocks, 256, 0, stream>>>(node_bf, csr_src, offs,
                                                            out, nN);
        else
            aggregate_f32_kernel<<<blocks, 256, 0, stream>>>(u_f, v_f, csr_src, offs,
                                                             odeg, out, nN, nU);
    }
}

// Round 5
// 259.360 us; speedup vs baseline: 10.8838x; 1.3226x over previous
//
#include <hip/hip_runtime.h>

// GCN aggregation, slack-CSR version (min random-line transactions).
//   out = diag(in_deg^-1/2) * A * diag(out_deg^-1/2) * concat(u_f, v_f)
//
// K1 build: per edge {p=atomicAdd(ideg[dst]); slack[dst*64+p]=src; atomicAdd(odeg[src])}
//           (overflow beyond 64 slots -> guarded ovf list; ~impossible for Poisson(16))
// K2 cast:  node_bf[n] = bf16(node_f[n] * rsqrt(max(odeg,1)))   (prescaled table)
// K3 agg :  wave per dst node, single <=64 batch, uint2 half-wave row-pairing,
//           fused in-degree norm. No scan, no cursor, 3 kernels + 1 memset.
//
// ws: ideg[nN] | odeg[nN] | ovf_cnt[4] | ovf[int2*OVF_CAP] | slack[nN*64] | node_bf[nN*128 bf16]

#define DFEAT 128
#define SLACK 64
#define OVF_CAP 262144

__global__ void build_kernel(const int* __restrict__ src,
                             const int* __restrict__ dst,
                             int* __restrict__ ideg,
                             int* __restrict__ odeg,
                             int* __restrict__ slack,
                             int2* __restrict__ ovf,
                             int* __restrict__ ovf_cnt,
                             int nE) {
    int t = blockIdx.x * blockDim.x + threadIdx.x;
    long base = (long)t * 4;
    if (base >= nE) return;
    if (base + 4 <= nE) {
        int4 s4 = ((const int4*)src)[t];
        int4 d4 = ((const int4*)dst)[t];
        int ss[4] = {s4.x, s4.y, s4.z, s4.w};
        int dd[4] = {d4.x, d4.y, d4.z, d4.w};
        #pragma unroll
        for (int j = 0; j < 4; ++j) {
            int s = ss[j], d = dd[j];
            atomicAdd(&odeg[s], 1);
            int p = atomicAdd(&ideg[d], 1);
            if (p < SLACK) {
                slack[(size_t)d * SLACK + p] = s;
            } else {
                int q = atomicAdd(ovf_cnt, 1);
                if (q < OVF_CAP) ovf[q] = make_int2(d, s);
            }
        }
    } else {
        for (long e = base; e < nE; ++e) {
            int s = src[e], d = dst[e];
            atomicAdd(&odeg[s], 1);
            int p = atomicAdd(&ideg[d], 1);
            if (p < SLACK) {
                slack[(size_t)d * SLACK + p] = s;
            } else {
                int q = atomicAdd(ovf_cnt, 1);
                if (q < OVF_CAP) ovf[q] = make_int2(d, s);
            }
        }
    }
}

__device__ __forceinline__ unsigned short f2bf(float x) {
    unsigned u = __float_as_uint(x);
    u += 0x7fffu + ((u >> 16) & 1u);   // round-to-nearest-even
    return (unsigned short)(u >> 16);
}
__device__ __forceinline__ float bflo(unsigned u) { return __uint_as_float(u << 16); }
__device__ __forceinline__ float bfhi(unsigned u) { return __uint_as_float(u & 0xffff0000u); }

// node_bf[n][128] = bf16(node_f[n] * rsqrt(max(odeg,1))); one thread per float4.
__global__ void cast_kernel(const float* __restrict__ u_f,
                            const float* __restrict__ v_f,
                            const int* __restrict__ odeg,
                            unsigned short* __restrict__ node_bf,
                            int nN, int nU) {
    long i = (long)blockIdx.x * blockDim.x + threadIdx.x;
    long n4 = (long)nN * (DFEAT / 4);
    if (i >= n4) return;
    int node = (int)(i >> 5);
    float norm = rsqrtf((float)max(odeg[node], 1));
    const float* base = (node < nU) ? (u_f + (size_t)node * DFEAT)
                                    : (v_f + (size_t)(node - nU) * DFEAT);
    float4 v = ((const float4*)base)[i & 31];
    ushort4 o;
    o.x = f2bf(v.x * norm);
    o.y = f2bf(v.y * norm);
    o.z = f2bf(v.z * norm);
    o.w = f2bf(v.w * norm);
    ((ushort4*)node_bf)[i] = o;
}

// One wave per dst node, 4 waves/block. Half-wave row-pairing: lanes 0-31 take
// row k, lanes 32-63 take row k+1; each lane loads uint2 = 4 bf16 features.
__launch_bounds__(256)
__global__ void aggregate_bf_kernel(const unsigned short* __restrict__ node_bf,
                                    const int* __restrict__ slack,
                                    const int* __restrict__ ideg,
                                    const int2* __restrict__ ovf,
                                    const int* __restrict__ ovf_cnt,
                                    float* __restrict__ out,
                                    int nN) {
    int lane = threadIdx.x & 63;
    int half = lane >> 5;
    int l32  = lane & 31;
    int wid  = threadIdx.x >> 6;
    int node = blockIdx.x * 4 + wid;
    if (node >= nN) return;

    int deg = ideg[node];
    int cnt = min(deg, SLACK);
    int sb = (lane < cnt) ? slack[(size_t)node * SLACK + lane] : 0;

    float ax = 0.f, ay = 0.f, az = 0.f, aw = 0.f;
    const uint2* tbl = (const uint2*)node_bf;   // 32 uint2 per row

    int k = 0;
    for (; k + 2 <= cnt; k += 2) {
        int sk = __shfl(sb, k + half, 64);
        uint2 w = tbl[(size_t)sk * 32 + l32];
        ax += bflo(w.x); ay += bfhi(w.x);
        az += bflo(w.y); aw += bfhi(w.y);
    }
    if (k < cnt) {   // odd tail: only half 0 contributes
        int sk = __shfl(sb, k, 64);
        uint2 w = tbl[(size_t)sk * 32 + l32];
        if (!half) {
            ax += bflo(w.x); ay += bfhi(w.x);
            az += bflo(w.y); aw += bfhi(w.y);
        }
    }
    if (deg > SLACK) {   // overflow entries (statistically never taken)
        int m = *ovf_cnt; if (m > OVF_CAP) m = OVF_CAP;
        for (int j = 0; j < m; ++j) {
            int2 os = ovf[j];
            if (os.x == node && !half) {
                uint2 w = tbl[(size_t)os.y * 32 + l32];
                ax += bflo(w.x); ay += bfhi(w.x);
                az += bflo(w.y); aw += bfhi(w.y);
            }
        }
    }

    // combine the two halves
    ax += __shfl_xor(ax, 32, 64);
    ay += __shfl_xor(ay, 32, 64);
    az += __shfl_xor(az, 32, 64);
    aw += __shfl_xor(aw, 32, 64);

    float inorm = rsqrtf((float)max(deg, 1));
    if (!half)
        ((float4*)(out + (size_t)node * DFEAT))[l32] =
            make_float4(ax * inorm, ay * inorm, az * inorm, aw * inorm);
}

// f32 fallback (small ws): gather f32 rows + odeg inline.
__launch_bounds__(256)
__global__ void aggregate_f32_kernel(const float* __restrict__ u_f,
                                     const float* __restrict__ v_f,
                                     const int* __restrict__ slack,
                                     const int* __restrict__ ideg,
                                     const int* __restrict__ odeg,
                                     const int2* __restrict__ ovf,
                                     const int* __restrict__ ovf_cnt,
                                     float* __restrict__ out,
                                     int nN, int nU) {
    int lane = threadIdx.x & 63;
    int wid  = threadIdx.x >> 6;
    int node = blockIdx.x * 4 + wid;
    if (node >= nN) return;

    int deg = ideg[node];
    int cnt = min(deg, SLACK);
    int   sb = 0;
    float nb = 0.f;
    if (lane < cnt) {
        sb = slack[(size_t)node * SLACK + lane];
        nb = rsqrtf((float)max(odeg[sb], 1));
    }
    float2 acc = make_float2(0.f, 0.f);
    for (int k = 0; k < cnt; ++k) {
        int   sk = __shfl(sb, k, 64);
        float nk = __shfl(nb, k, 64);
        const float* row = (sk < nU) ? (u_f + (size_t)sk * DFEAT)
                                     : (v_f + (size_t)(sk - nU) * DFEAT);
        float2 v = ((const float2*)row)[lane];
        acc.x += v.x * nk;
        acc.y += v.y * nk;
    }
    if (deg > SLACK) {
        int m = *ovf_cnt; if (m > OVF_CAP) m = OVF_CAP;
        for (int j = 0; j < m; ++j) {
            int2 os = ovf[j];
            if (os.x == node) {
                int sk = os.y;
                float nk = rsqrtf((float)max(odeg[sk], 1));
                const float* row = (sk < nU) ? (u_f + (size_t)sk * DFEAT)
                                             : (v_f + (size_t)(sk - nU) * DFEAT);
                float2 v = ((const float2*)row)[lane];
                acc.x += v.x * nk;
                acc.y += v.y * nk;
            }
        }
    }
    float inorm = rsqrtf((float)max(deg, 1));
    acc.x *= inorm; acc.y *= inorm;
    ((float2*)(out + (size_t)node * DFEAT))[lane] = acc;
}

extern "C" void kernel_launch(void* const* d_in, const int* in_sizes, int n_in,
                              void* d_out, int out_size, void* d_ws, size_t ws_size,
                              hipStream_t stream) {
    const float* u_f = (const float*)d_in[0];
    const float* v_f = (const float*)d_in[1];
    const int*   src = (const int*)d_in[2];
    const int*   dst = (const int*)d_in[3];
    float* out = (float*)d_out;

    int nU = in_sizes[0] / DFEAT;
    int nV = in_sizes[1] / DFEAT;
    int nN = nU + nV;
    int nE = in_sizes[2];

    int*  ideg    = (int*)d_ws;
    int*  odeg    = ideg + nN;
    int*  ovf_cnt = odeg + nN;              // 4 ints (pad)
    int2* ovf     = (int2*)(ovf_cnt + 4);
    int*  slack   = (int*)(ovf + OVF_CAP);
    unsigned short* node_bf = (unsigned short*)(slack + (size_t)nN * SLACK);
    size_t need_bf = ((char*)node_bf - (char*)d_ws) + (size_t)nN * DFEAT * sizeof(unsigned short);
    bool use_bf = (ws_size >= need_bf);

    // zero ideg | odeg | ovf_cnt (contiguous); slack/ovf need no init
    hipMemsetAsync(d_ws, 0, ((size_t)2 * nN + 4) * sizeof(int), stream);

    {   // K1: fused degrees + slack-CSR build
        long nT = ((long)nE + 3) / 4;
        int blocks = (int)((nT + 255) / 256);
        build_kernel<<<blocks, 256, 0, stream>>>(src, dst, ideg, odeg, slack,
                                                 ovf, ovf_cnt, nE);
    }
    if (use_bf) {   // K2: bf16 prescaled node table
        long n4 = (long)nN * (DFEAT / 4);
        int blocks = (int)((n4 + 255) / 256);
        cast_kernel<<<blocks, 256, 0, stream>>>(u_f, v_f, odeg, node_bf, nN, nU);
    }
    {   // K3: aggregate
        int blocks = (nN + 3) / 4;
        if (use_bf)
            aggregate_bf_kernel<<<blocks, 256, 0, stream>>>(node_bf, slack, ideg,
                                                            ovf, ovf_cnt, out, nN);
        else
            aggregate_f32_kernel<<<blocks, 256, 0, stream>>>(u_f, v_f, slack, ideg,
                                                             odeg, ovf, ovf_cnt,
                                                             out, nN, nU);
    }
}

// Round 6
// 214.085 us; speedup vs baseline: 13.1855x; 1.2115x over previous
//
#include <hip/hip_runtime.h>

// GCN aggregation — bucketed (radix-partition) build + bf16 gather-sum.
//   out = diag(in_deg^-1/2) * A * diag(out_deg^-1/2) * concat(u_f, v_f)
//
// New build pipeline (all random work converted to LDS-local / L2-local):
//   init: gcurD[b]=gcurS[b]=b*BCAP
//   P1s : partition src keys into buckets (LDS staged, coalesced flush)
//   P2s : per-bucket LDS histogram -> odeg (coalesced atomicAdd)
//   P1d : partition (dst,src) pairs into buckets
//   P2d : per-bucket LDS slot-alloc -> slack rows (L2-local) + ideg
//   OVF : rare partition-overflow fixup (random atomics; empty in practice)
//   cast: node_bf = bf16(node_f * rsqrt(max(odeg,1)))
//   agg : wave per dst node, uint2 half-wave pairing, fused in-norm
//
// Fallback (small ws): round-5 slack-CSR random-atomic build.

#define DFEAT 128
#define SLACK 64
#define OVF2_CAP 65536      // slack-overflow (d,s) pairs, consumed by aggregate
#define OVFD_CAP 65536      // partition-overflow (d,s) pairs, fixup kernel
#define BSHIFT 7            // 128 nodes per bucket
#define BNODES (1 << BSHIFT)
#define MAXBUK 1024         // supports nN <= 131072
#define BCAP 4096           // per-bucket capacity in partitioned arrays
#define CH 6144             // edges per partition chunk (LDS-staged)

// ---------------- init ----------------
__global__ void init_kernel(int* __restrict__ gcurD, int* __restrict__ gcurS,
                            int nbuk) {
    int b = blockIdx.x * blockDim.x + threadIdx.x;
    if (b < nbuk) { gcurD[b] = b * BCAP; gcurS[b] = b * BCAP; }
}

// ---------------- partition: (dst,src) pairs ----------------
__global__ __launch_bounds__(256)
void partition_pairs_kernel(const int* __restrict__ dst,
                            const int* __restrict__ src,
                            int* __restrict__ gcur,
                            uint2* __restrict__ part,
                            int2* __restrict__ ovf,
                            int* __restrict__ ovf_cnt,
                            int nE, int nbuk) {
    __shared__ int hist[MAXBUK];     // counts -> lbase -> running cursor
    __shared__ int dlt[MAXBUK];      // gpos - lbase per bucket
    __shared__ int wsum[4];
    __shared__ unsigned sk[CH];
    __shared__ unsigned sv[CH];

    int tid = threadIdx.x;
    long base = (long)blockIdx.x * CH;
    int n = (int)(((long)nE - base) < CH ? ((long)nE - base) : CH);
    if (n <= 0) return;

    for (int b = tid; b < nbuk; b += 256) hist[b] = 0;
    __syncthreads();
    for (int i = tid; i < n; i += 256)
        atomicAdd(&hist[((unsigned)dst[base + i]) >> BSHIFT], 1);
    __syncthreads();

    // exclusive scan of hist[0..nbuk); thread t owns bins 4t..4t+3
    int b0 = tid * 4;
    int c0 = 0, c1 = 0, c2 = 0, c3 = 0, sum = 0;
    if (b0 < nbuk) {
        c0 = hist[b0];
        c1 = (b0 + 1 < nbuk) ? hist[b0 + 1] : 0;
        c2 = (b0 + 2 < nbuk) ? hist[b0 + 2] : 0;
        c3 = (b0 + 3 < nbuk) ? hist[b0 + 3] : 0;
        sum = c0 + c1 + c2 + c3;
    }
    int lane = tid & 63, wid = tid >> 6;
    int x = sum;
    #pragma unroll
    for (int off = 1; off < 64; off <<= 1) {
        int t = __shfl_up(x, off, 64);
        if (lane >= off) x += t;
    }
    if (lane == 63) wsum[wid] = x;
    __syncthreads();
    int wpre = 0;
    for (int w = 0; w < wid; ++w) wpre += wsum[w];
    int excl = wpre + x - sum;           // exclusive prefix of this thread's group
    __syncthreads();
    if (b0 < nbuk) {
        // write lbase and reserve global space per nonempty bin
        int lb = excl;
        hist[b0] = lb;
        if (c0) { int g = atomicAdd(&gcur[b0], c0); dlt[b0] = g - lb; }
        lb += c0;
        if (b0 + 1 < nbuk) {
            hist[b0 + 1] = lb;
            if (c1) { int g = atomicAdd(&gcur[b0 + 1], c1); dlt[b0 + 1] = g - lb; }
            lb += c1;
        }
        if (b0 + 2 < nbuk) {
            hist[b0 + 2] = lb;
            if (c2) { int g = atomicAdd(&gcur[b0 + 2], c2); dlt[b0 + 2] = g - lb; }
            lb += c2;
        }
        if (b0 + 3 < nbuk) {
            hist[b0 + 3] = lb;
            if (c3) { int g = atomicAdd(&gcur[b0 + 3], c3); dlt[b0 + 3] = g - lb; }
        }
    }
    __syncthreads();

    // scatter into LDS stage (bucket-sorted order)
    for (int i = tid; i < n; i += 256) {
        unsigned d = (unsigned)dst[base + i];
        unsigned s = (unsigned)src[base + i];
        int slot = atomicAdd(&hist[d >> BSHIFT], 1);
        sk[slot] = d; sv[slot] = s;
    }
    __syncthreads();

    // coalesced flush: dest = dlt[bucket] + slot
    for (int i = tid; i < n; i += 256) {
        unsigned d = sk[i], s = sv[i];
        int b = (int)(d >> BSHIFT);
        long dest = (long)dlt[b] + i;
        long capend = (long)(b + 1) * BCAP;
        if (dest < capend) {
            part[dest] = make_uint2(d, s);
        } else {
            int q = atomicAdd(ovf_cnt, 1);
            if (q < OVFD_CAP) ovf[q] = make_int2((int)d, (int)s);
        }
    }
}

// ---------------- partition: src keys only ----------------
__global__ __launch_bounds__(256)
void partition_keys_kernel(const int* __restrict__ key,
                           int* __restrict__ gcur,
                           unsigned* __restrict__ part,
                           int* __restrict__ spill_hist,  // odeg; spills add here
                           int nE, int nbuk) {
    __shared__ int hist[MAXBUK];
    __shared__ int dlt[MAXBUK];
    __shared__ int wsum[4];
    __shared__ unsigned sk[CH];

    int tid = threadIdx.x;
    long base = (long)blockIdx.x * CH;
    int n = (int)(((long)nE - base) < CH ? ((long)nE - base) : CH);
    if (n <= 0) return;

    for (int b = tid; b < nbuk; b += 256) hist[b] = 0;
    __syncthreads();
    for (int i = tid; i < n; i += 256)
        atomicAdd(&hist[((unsigned)key[base + i]) >> BSHIFT], 1);
    __syncthreads();

    int b0 = tid * 4;
    int c0 = 0, c1 = 0, c2 = 0, c3 = 0, sum = 0;
    if (b0 < nbuk) {
        c0 = hist[b0];
        c1 = (b0 + 1 < nbuk) ? hist[b0 + 1] : 0;
        c2 = (b0 + 2 < nbuk) ? hist[b0 + 2] : 0;
        c3 = (b0 + 3 < nbuk) ? hist[b0 + 3] : 0;
        sum = c0 + c1 + c2 + c3;
    }
    int lane = tid & 63, wid = tid >> 6;
    int x = sum;
    #pragma unroll
    for (int off = 1; off < 64; off <<= 1) {
        int t = __shfl_up(x, off, 64);
        if (lane >= off) x += t;
    }
    if (lane == 63) wsum[wid] = x;
    __syncthreads();
    int wpre = 0;
    for (int w = 0; w < wid; ++w) wpre += wsum[w];
    int excl = wpre + x - sum;
    __syncthreads();
    if (b0 < nbuk) {
        int lb = excl;
        hist[b0] = lb;
        if (c0) { int g = atomicAdd(&gcur[b0], c0); dlt[b0] = g - lb; }
        lb += c0;
        if (b0 + 1 < nbuk) {
            hist[b0 + 1] = lb;
            if (c1) { int g = atomicAdd(&gcur[b0 + 1], c1); dlt[b0 + 1] = g - lb; }
            lb += c1;
        }
        if (b0 + 2 < nbuk) {
            hist[b0 + 2] = lb;
            if (c2) { int g = atomicAdd(&gcur[b0 + 2], c2); dlt[b0 + 2] = g - lb; }
            lb += c2;
        }
        if (b0 + 3 < nbuk) {
            hist[b0 + 3] = lb;
            if (c3) { int g = atomicAdd(&gcur[b0 + 3], c3); dlt[b0 + 3] = g - lb; }
        }
    }
    __syncthreads();

    for (int i = tid; i < n; i += 256) {
        unsigned k = (unsigned)key[base + i];
        int slot = atomicAdd(&hist[k >> BSHIFT], 1);
        sk[slot] = k;
    }
    __syncthreads();

    for (int i = tid; i < n; i += 256) {
        unsigned k = sk[i];
        int b = (int)(k >> BSHIFT);
        long dest = (long)dlt[b] + i;
        long capend = (long)(b + 1) * BCAP;
        if (dest < capend) part[dest] = k;
        else atomicAdd(&spill_hist[k], 1);
    }
}

// ---------------- phase-2: CSR (slack rows) + ideg ----------------
__global__ __launch_bounds__(256)
void csr_phase2_kernel(const uint2* __restrict__ part,
                       const int* __restrict__ gcur,
                       int* __restrict__ ideg,
                       int* __restrict__ slack,
                       int2* __restrict__ ovf2,
                       int* __restrict__ ovf2_cnt,
                       int nN) {
    __shared__ int bins[BNODES];
    int tid = threadIdx.x;
    int bucket = blockIdx.x;
    int nodeBase = bucket << BSHIFT;
    for (int b = tid; b < BNODES; b += 256) bins[b] = 0;
    __syncthreads();
    int start = bucket * BCAP;
    int endv = gcur[bucket];
    if (endv > start + BCAP) endv = start + BCAP;
    for (int i = start + tid; i < endv; i += 256) {
        uint2 p = part[i];
        int d = (int)p.x, s = (int)p.y;
        int slot = atomicAdd(&bins[d - nodeBase], 1);
        if (slot < SLACK) {
            slack[(size_t)d * SLACK + slot] = s;
        } else {
            int q = atomicAdd(ovf2_cnt, 1);
            if (q < OVF2_CAP) ovf2[q] = make_int2(d, s);
        }
    }
    __syncthreads();
    for (int b = tid; b < BNODES; b += 256) {
        int node = nodeBase + b;
        if (node < nN && bins[b]) atomicAdd(&ideg[node], bins[b]);
    }
}

// ---------------- phase-2: odeg histogram ----------------
__global__ __launch_bounds__(256)
void odeg_phase2_kernel(const unsigned* __restrict__ part,
                        const int* __restrict__ gcur,
                        int* __restrict__ odeg, int nN) {
    __shared__ int bins[BNODES];
    int tid = threadIdx.x;
    int bucket = blockIdx.x;
    int nodeBase = bucket << BSHIFT;
    for (int b = tid; b < BNODES; b += 256) bins[b] = 0;
    __syncthreads();
    int start = bucket * BCAP;
    int endv = gcur[bucket];
    if (endv > start + BCAP) endv = start + BCAP;
    for (int i = start + tid; i < endv; i += 256)
        atomicAdd(&bins[(int)part[i] - nodeBase], 1);
    __syncthreads();
    for (int b = tid; b < BNODES; b += 256) {
        int node = nodeBase + b;
        if (node < nN && bins[b]) atomicAdd(&odeg[node], bins[b]);
    }
}

// ---------------- partition-overflow fixup (empty in practice) ----------------
__global__ void ovfd_fix_kernel(const int2* __restrict__ ovf,
                                const int* __restrict__ ovf_cnt,
                                int* __restrict__ ideg,
                                int* __restrict__ slack,
                                int2* __restrict__ ovf2,
                                int* __restrict__ ovf2_cnt) {
    int n = *ovf_cnt; if (n > OVFD_CAP) n = OVFD_CAP;
    int i = blockIdx.x * blockDim.x + threadIdx.x;
    if (i >= n) return;
    int d = ovf[i].x, s = ovf[i].y;
    int p = atomicAdd(&ideg[d], 1);
    if (p < SLACK) {
        slack[(size_t)d * SLACK + p] = s;
    } else {
        int q = atomicAdd(ovf2_cnt, 1);
        if (q < OVF2_CAP) ovf2[q] = make_int2(d, s);
    }
}

// ---------------- bf16 helpers ----------------
__device__ __forceinline__ unsigned short f2bf(float x) {
    unsigned u = __float_as_uint(x);
    u += 0x7fffu + ((u >> 16) & 1u);   // round-to-nearest-even
    return (unsigned short)(u >> 16);
}
__device__ __forceinline__ float bflo(unsigned u) { return __uint_as_float(u << 16); }
__device__ __forceinline__ float bfhi(unsigned u) { return __uint_as_float(u & 0xffff0000u); }

// node_bf[n][128] = bf16(node_f[n] * rsqrt(max(odeg,1))); one thread per float4.
__global__ void cast_kernel(const float* __restrict__ u_f,
                            const float* __restrict__ v_f,
                            const int* __restrict__ odeg,
                            unsigned short* __restrict__ node_bf,
                            int nN, int nU) {
    long i = (long)blockIdx.x * blockDim.x + threadIdx.x;
    long n4 = (long)nN * (DFEAT / 4);
    if (i >= n4) return;
    int node = (int)(i >> 5);
    float norm = rsqrtf((float)max(odeg[node], 1));
    const float* base = (node < nU) ? (u_f + (size_t)node * DFEAT)
                                    : (v_f + (size_t)(node - nU) * DFEAT);
    float4 v = ((const float4*)base)[i & 31];
    ushort4 o;
    o.x = f2bf(v.x * norm);
    o.y = f2bf(v.y * norm);
    o.z = f2bf(v.z * norm);
    o.w = f2bf(v.w * norm);
    ((ushort4*)node_bf)[i] = o;
}

// ---------------- aggregate (bf16 table) ----------------
__launch_bounds__(256)
__global__ void aggregate_bf_kernel(const unsigned short* __restrict__ node_bf,
                                    const int* __restrict__ slack,
                                    const int* __restrict__ ideg,
                                    const int2* __restrict__ ovf2,
                                    const int* __restrict__ ovf2_cnt,
                                    float* __restrict__ out,
                                    int nN) {
    int lane = threadIdx.x & 63;
    int half = lane >> 5;
    int l32  = lane & 31;
    int wid  = threadIdx.x >> 6;
    int node = blockIdx.x * 4 + wid;
    if (node >= nN) return;

    int deg = ideg[node];
    int cnt = min(deg, SLACK);
    int sb = (lane < cnt) ? slack[(size_t)node * SLACK + lane] : 0;

    float ax = 0.f, ay = 0.f, az = 0.f, aw = 0.f;
    const uint2* tbl = (const uint2*)node_bf;   // 32 uint2 per row

    int k = 0;
    for (; k + 2 <= cnt; k += 2) {
        int sk = __shfl(sb, k + half, 64);
        uint2 w = tbl[(size_t)sk * 32 + l32];
        ax += bflo(w.x); ay += bfhi(w.x);
        az += bflo(w.y); aw += bfhi(w.y);
    }
    if (k < cnt) {
        int sk = __shfl(sb, k, 64);
        uint2 w = tbl[(size_t)sk * 32 + l32];
        if (!half) {
            ax += bflo(w.x); ay += bfhi(w.x);
            az += bflo(w.y); aw += bfhi(w.y);
        }
    }
    if (deg > SLACK) {
        int m = *ovf2_cnt; if (m > OVF2_CAP) m = OVF2_CAP;
        for (int j = 0; j < m; ++j) {
            int2 os = ovf2[j];
            if (os.x == node && !half) {
                uint2 w = tbl[(size_t)os.y * 32 + l32];
                ax += bflo(w.x); ay += bfhi(w.x);
                az += bflo(w.y); aw += bfhi(w.y);
            }
        }
    }

    ax += __shfl_xor(ax, 32, 64);
    ay += __shfl_xor(ay, 32, 64);
    az += __shfl_xor(az, 32, 64);
    aw += __shfl_xor(aw, 32, 64);

    float inorm = rsqrtf((float)max(deg, 1));
    if (!half)
        ((float4*)(out + (size_t)node * DFEAT))[l32] =
            make_float4(ax * inorm, ay * inorm, az * inorm, aw * inorm);
}

// ---------------- fallback: round-5 random-atomic build ----------------
__global__ void build_kernel(const int* __restrict__ src,
                             const int* __restrict__ dst,
                             int* __restrict__ ideg,
                             int* __restrict__ odeg,
                             int* __restrict__ slack,
                             int2* __restrict__ ovf2,
                             int* __restrict__ ovf2_cnt,
                             int nE) {
    int t = blockIdx.x * blockDim.x + threadIdx.x;
    long base = (long)t * 4;
    if (base >= nE) return;
    long lim = base + 4 < (long)nE ? base + 4 : (long)nE;
    for (long e = base; e < lim; ++e) {
        int s = src[e], d = dst[e];
        atomicAdd(&odeg[s], 1);
        int p = atomicAdd(&ideg[d], 1);
        if (p < SLACK) {
            slack[(size_t)d * SLACK + p] = s;
        } else {
            int q = atomicAdd(ovf2_cnt, 1);
            if (q < OVF2_CAP) ovf2[q] = make_int2(d, s);
        }
    }
}

// fallback aggregate without bf16 table
__launch_bounds__(256)
__global__ void aggregate_f32_kernel(const float* __restrict__ u_f,
                                     const float* __restrict__ v_f,
                                     const int* __restrict__ slack,
                                     const int* __restrict__ ideg,
                                     const int* __restrict__ odeg,
                                     const int2* __restrict__ ovf2,
                                     const int* __restrict__ ovf2_cnt,
                                     float* __restrict__ out,
                                     int nN, int nU) {
    int lane = threadIdx.x & 63;
    int wid  = threadIdx.x >> 6;
    int node = blockIdx.x * 4 + wid;
    if (node >= nN) return;

    int deg = ideg[node];
    int cnt = min(deg, SLACK);
    int   sb = 0;
    float nb = 0.f;
    if (lane < cnt) {
        sb = slack[(size_t)node * SLACK + lane];
        nb = rsqrtf((float)max(odeg[sb], 1));
    }
    float2 acc = make_float2(0.f, 0.f);
    for (int k = 0; k < cnt; ++k) {
        int   sk = __shfl(sb, k, 64);
        float nk = __shfl(nb, k, 64);
        const float* row = (sk < nU) ? (u_f + (size_t)sk * DFEAT)
                                     : (v_f + (size_t)(sk - nU) * DFEAT);
        float2 v = ((const float2*)row)[lane];
        acc.x += v.x * nk;
        acc.y += v.y * nk;
    }
    if (deg > SLACK) {
        int m = *ovf2_cnt; if (m > OVF2_CAP) m = OVF2_CAP;
        for (int j = 0; j < m; ++j) {
            int2 os = ovf2[j];
            if (os.x == node) {
                int sk = os.y;
                float nk = rsqrtf((float)max(odeg[sk], 1));
                const float* row = (sk < nU) ? (u_f + (size_t)sk * DFEAT)
                                             : (v_f + (size_t)(sk - nU) * DFEAT);
                float2 v = ((const float2*)row)[lane];
                acc.x += v.x * nk;
                acc.y += v.y * nk;
            }
        }
    }
    float inorm = rsqrtf((float)max(deg, 1));
    acc.x *= inorm; acc.y *= inorm;
    ((float2*)(out + (size_t)node * DFEAT))[lane] = acc;
}

extern "C" void kernel_launch(void* const* d_in, const int* in_sizes, int n_in,
                              void* d_out, int out_size, void* d_ws, size_t ws_size,
                              hipStream_t stream) {
    const float* u_f = (const float*)d_in[0];
    const float* v_f = (const float*)d_in[1];
    const int*   src = (const int*)d_in[2];
    const int*   dst = (const int*)d_in[3];
    float* out = (float*)d_out;

    int nU = in_sizes[0] / DFEAT;
    int nV = in_sizes[1] / DFEAT;
    int nN = nU + nV;
    int nE = in_sizes[2];
    int nbuk = (nN + BNODES - 1) >> BSHIFT;

    // workspace layout (ints)
    int*  ideg  = (int*)d_ws;
    int*  odeg  = ideg + nN;
    int*  cnts  = odeg + nN;               // [0]=ovf2_cnt, [1]=ovfD_cnt
    int2* ovf2  = (int2*)(cnts + 8);
    int2* ovfD  = ovf2 + OVF2_CAP;
    int*  gcurD = (int*)(ovfD + OVFD_CAP);
    int*  gcurS = gcurD + MAXBUK;
    int*  slack = gcurS + MAXBUK;
    size_t fixedInts = (size_t)2 * nN + 8 + 2 * OVF2_CAP + 2 * OVFD_CAP + 2 * MAXBUK;
    size_t slackInts = (size_t)nN * SLACK;
    uint2*    partD   = (uint2*)(slack + slackInts);
    unsigned* partS   = (unsigned*)(partD + (size_t)nbuk * BCAP);
    size_t partDInts  = 2 * (size_t)nbuk * BCAP;
    size_t partSInts  = (size_t)nbuk * BCAP;
    size_t bfInts     = (size_t)nN * (DFEAT / 2);   // nN*128 ushort = nN*64 ints
    size_t unionInts  = partSInts > bfInts ? partSInts : bfInts;

    size_t needNew   = (fixedInts + slackInts + partDInts + unionInts) * 4;
    size_t needOldBf = (fixedInts + slackInts + bfInts) * 4;
    size_t needOld   = (fixedInts + slackInts) * 4;

    bool use_new    = (nN <= (MAXBUK << BSHIFT)) && (ws_size >= needNew);
    bool use_bf_old = (ws_size >= needOldBf);
    (void)needOld;

    // zero degree histograms + overflow counters (ws poisoned 0xAA, never re-poisoned)
    hipMemsetAsync(d_ws, 0, ((size_t)2 * nN + 8) * sizeof(int), stream);

    if (use_new) {
        unsigned short* node_bf = (unsigned short*)partS;  // overlays partS (dead by then)
        int nCh = (nE + CH - 1) / CH;

        init_kernel<<<(nbuk + 255) / 256, 256, 0, stream>>>(gcurD, gcurS, nbuk);
        partition_keys_kernel<<<nCh, 256, 0, stream>>>(src, gcurS, partS, odeg,
                                                       nE, nbuk);
        odeg_phase2_kernel<<<nbuk, 256, 0, stream>>>(partS, gcurS, odeg, nN);
        partition_pairs_kernel<<<nCh, 256, 0, stream>>>(dst, src, gcurD, partD,
                                                        ovfD, cnts + 1, nE, nbuk);
        csr_phase2_kernel<<<nbuk, 256, 0, stream>>>(partD, gcurD, ideg, slack,
                                                    ovf2, cnts + 0, nN);
        ovfd_fix_kernel<<<OVFD_CAP / 256, 256, 0, stream>>>(ovfD, cnts + 1, ideg,
                                                            slack, ovf2, cnts + 0);
        {
            long n4 = (long)nN * (DFEAT / 4);
            cast_kernel<<<(int)((n4 + 255) / 256), 256, 0, stream>>>(u_f, v_f, odeg,
                                                                     node_bf, nN, nU);
        }
        aggregate_bf_kernel<<<(nN + 3) / 4, 256, 0, stream>>>(node_bf, slack, ideg,
                                                              ovf2, cnts + 0, out, nN);
    } else {
        // round-5 fallback
        long nT = ((long)nE + 3) / 4;
        build_kernel<<<(int)((nT + 255) / 256), 256, 0, stream>>>(src, dst, ideg,
                                                                  odeg, slack,
                                                                  ovf2, cnts + 0, nE);
        if (use_bf_old) {
            unsigned short* node_bf = (unsigned short*)partD;  // right after slack
            long n4 = (long)nN * (DFEAT / 4);
            cast_kernel<<<(int)((n4 + 255) / 256), 256, 0, stream>>>(u_f, v_f, odeg,
                                                                     node_bf, nN, nU);
            aggregate_bf_kernel<<<(nN + 3) / 4, 256, 0, stream>>>(node_bf, slack,
                                                                  ideg, ovf2,
                                                                  cnts + 0, out, nN);
        } else {
            aggregate_f32_kernel<<<(nN + 3) / 4, 256, 0, stream>>>(u_f, v_f, slack,
                                                                   ideg, odeg, ovf2,
                                                                   cnts + 0, out,
                                                                   nN, nU);
        }
    }
}